// Round 4
// baseline (709.878 us; speedup 1.0000x reference)
//
#include <hip/hip_runtime.h>

typedef short s16x8 __attribute__((ext_vector_type(8)));
typedef float f32x4 __attribute__((ext_vector_type(4)));

#define T_STEPS 128
#define BN_EPS 1e-5f
#define LROW 392   // X row stride in shorts (384 + 8 pad; 196 dw % 32 = 4)
#define EXS 36     // EX innermost stride in floats (32 + 4 pad; odd multiple of 4)

__device__ __forceinline__ unsigned short f2bf(float f) {
  unsigned u = __float_as_uint(f);
  u += 0x7FFFu + ((u >> 16) & 1u);
  return (unsigned short)(u >> 16);
}
__device__ __forceinline__ unsigned cvtpk(float a, float b) {
  unsigned r;
  asm("v_cvt_pk_bf16_f32 %0, %1, %2" : "=v"(r) : "v"(a), "v"(b));
  return r;  // lo16 = bf16(a), hi16 = bf16(b)
}
__device__ __forceinline__ float sigm(float x) {
  return __builtin_amdgcn_rcpf(1.0f + __expf(-x));
}
__device__ __forceinline__ float tanh_(float x) {
  return 1.0f - 2.0f * __builtin_amdgcn_rcpf(1.0f + __expf(2.0f * x));
}

// ---------- fused: per-t input moments + embedding Linear/BN/ReLU fold ----------
__global__ void prep_e_kernel(const float* __restrict__ inp,
                              const float* __restrict__ W_emb, const float* __restrict__ b_emb,
                              const float* __restrict__ gamma, const float* __restrict__ beta,
                              float* __restrict__ cA, float* __restrict__ cB, float* __restrict__ cC,
                              int B, float invB) {
  int t = blockIdx.x, tid = threadIdx.x;
  float s0 = 0.f, s1 = 0.f, q0 = 0.f, q1 = 0.f, pp = 0.f;
  for (int b = tid; b < B; b += 256) {
    float2 x = *(const float2*)(inp + (size_t)b * (2 * T_STEPS) + 2 * t);
    s0 += x.x; s1 += x.y; q0 += x.x * x.x; q1 += x.y * x.y; pp += x.x * x.y;
  }
  float v[5] = {s0, s1, q0, q1, pp};
  #pragma unroll
  for (int i = 0; i < 5; ++i) {
    float x = v[i];
    #pragma unroll
    for (int o = 32; o > 0; o >>= 1) x += __shfl_down(x, o);
    v[i] = x;
  }
  __shared__ float red[4][5];
  __shared__ float tot[5];
  if ((tid & 63) == 0) {
    #pragma unroll
    for (int i = 0; i < 5; ++i) red[tid >> 6][i] = v[i];
  }
  __syncthreads();
  if (tid == 0) {
    #pragma unroll
    for (int i = 0; i < 5; ++i) tot[i] = red[0][i] + red[1][i] + red[2][i] + red[3][i];
  }
  __syncthreads();
  if (tid < 128) {
    int j = tid;
    float m0 = tot[0] * invB, m1 = tot[1] * invB;
    float q0m = tot[2] * invB, q1m = tot[3] * invB, p = tot[4] * invB;
    float v00 = q0m - m0 * m0, v11 = q1m - m1 * m1, v01 = p - m0 * m1;
    float w0 = W_emb[2 * j], w1 = W_emb[2 * j + 1];
    float mu  = w0 * m0 + w1 * m1 + b_emb[j];
    float var = w0 * w0 * v00 + w1 * w1 * v11 + 2.f * w0 * w1 * v01;
    float a = gamma[j] * rsqrtf(var + BN_EPS);
    int idx = t * 128 + j;
    cA[idx] = a * w0;
    cB[idx] = a * w1;
    cC[idx] = beta[j] + a * (b_emb[j] - mu);
  }
}

// ---------------- weights -> bf16 (gate concat + padded W_out) ----------------
__global__ void prepw_kernel(const float* __restrict__ Wih, const float* __restrict__ Whh,
                             const float* __restrict__ Wout,
                             unsigned short* __restrict__ Wb, unsigned short* __restrict__ Wob) {
  int idx = blockIdx.x * 256 + threadIdx.x;
  if (idx < 512 * 256) {
    int n = idx >> 8, k = idx & 255;
    float w = (k < 128) ? Wih[n * 128 + k] : Whh[n * 128 + (k - 128)];
    Wb[idx] = f2bf(w);
  } else if (idx < 512 * 256 + 16 * 128) {
    int i2 = idx - 512 * 256;
    int d = i2 >> 7, k = i2 & 127;
    Wob[i2] = (d < 5) ? f2bf(Wout[d * 128 + k]) : (unsigned short)0;
  }
}

// --------------------------- the recurrence ---------------------------------
// 1024 thr = 16 waves, 32 batch rows/block. K-split: waves 0-7 e-half (k 0..127),
// waves 8-15 h-half (k 128..255); wave cg = wave&7 owns gate-cols [16cg,16cg+16)
// of all 4 gates. Partial gates cross once/step via padded LDS EX buffer.
// X cols: [0,128) e | [128,256) h0 | [256,384) h1.
__global__ __launch_bounds__(1024) void lstm_kernel(
    const float* __restrict__ inp,
    const float* __restrict__ cA, const float* __restrict__ cB, const float* __restrict__ cC,
    const unsigned short* __restrict__ Wb, const unsigned short* __restrict__ Wob,
    const float* __restrict__ bih, const float* __restrict__ bhh,
    float* __restrict__ outz, float* __restrict__ hout, float* __restrict__ cout) {
  __shared__ __align__(16) short X[32][LROW];               // 25088 B
  __shared__ __align__(16) unsigned short WO[16][136];      //  4352 B
  __shared__ __align__(16) float EX[8][4][16][EXS];         // 73728 B

  const int tid  = threadIdx.x;
  const int wave = tid >> 6;
  const int lane = tid & 63;
  const int l15  = lane & 15;
  const int lk   = lane >> 4;
  const int eh   = (wave >> 3);        // 0 = e-wave, 1 = h-wave
  const int cg   = wave & 7;
  const int b0   = blockIdx.x * 32;
  const int em   = tid >> 5;           // 0..31
  const int ec4  = (tid & 31) * 4;

  // per-wave weights: 4 gates x 16 cols x K-half  (64 VGPRs)
  s16x8 wfrag[4][4];
  #pragma unroll
  for (int g = 0; g < 4; ++g)
    #pragma unroll
    for (int kk = 0; kk < 4; ++kk)
      wfrag[g][kk] = *(const s16x8*)(Wb + (size_t)(g * 128 + cg * 16 + l15) * 256 + eh * 128 + kk * 32 + lk * 8);
  float biasg[4];
  #pragma unroll
  for (int g = 0; g < 4; ++g) {
    int n = g * 128 + cg * 16 + l15;
    biasg[g] = eh ? 0.f : (bih[n] + bhh[n]);   // bias contributed by e-half only
  }

  // stage W_out into LDS (2 elems/thread)
  {
    int i0 = tid * 2;
    int d = i0 >> 7, k = i0 & 127;
    *(unsigned*)&WO[d][k] = *(const unsigned*)(Wob + i0);
  }

  auto do_e = [&](int tn) {
    float2 xv = *(const float2*)(inp + (size_t)(b0 + em) * (2 * T_STEPS) + 2 * tn);
    float4 va = *(const float4*)(cA + tn * 128 + ec4);
    float4 vb = *(const float4*)(cB + tn * 128 + ec4);
    float4 vc = *(const float4*)(cC + tn * 128 + ec4);
    float e0 = fmaxf(0.f, vc.x + va.x * xv.x + vb.x * xv.y);
    float e1 = fmaxf(0.f, vc.y + va.y * xv.x + vb.y * xv.y);
    float e2 = fmaxf(0.f, vc.z + va.z * xv.x + vb.z * xv.y);
    float e3 = fmaxf(0.f, vc.w + va.w * xv.x + vb.w * xv.y);
    *(uint2*)&X[em][ec4] = make_uint2(cvtpk(e0, e1), cvtpk(e2, e3));
  };

  // init: zero h-buffer0, e(0)
  *(uint2*)&X[em][128 + ec4] = make_uint2(0u, 0u);
  do_e(0);
  __syncthreads();

  float creg[4] = {0.f, 0.f, 0.f, 0.f};
  float hreg[4] = {0.f, 0.f, 0.f, 0.f};
  const int colX    = cg * 16 + l15;     // this lane's h-col
  const int keep_r0 = eh ? 16 : 0;       // row-tile this wave keeps (pointwise)
  const int rowP    = keep_r0 + lk * 4;

  #pragma unroll 1
  for (int t = 0; t < T_STEPS; ++t) {
    const int rb = 128 + (t & 1) * 128;
    const int wb = 128 + ((t + 1) & 1) * 128;
    const int abase = eh ? rb : 0;

    // A: partial gates for both row-tiles over this wave's K-half
    f32x4 acc0[4], acc1[4];
    #pragma unroll
    for (int g = 0; g < 4; ++g) {
      f32x4 v = {biasg[g], biasg[g], biasg[g], biasg[g]};
      acc0[g] = v; acc1[g] = v;
    }
    #pragma unroll
    for (int kk = 0; kk < 4; ++kk) {
      const int coff = abase + kk * 32 + lk * 8;
      s16x8 a0 = *(const s16x8*)&X[l15][coff];
      s16x8 a1 = *(const s16x8*)&X[16 + l15][coff];
      #pragma unroll
      for (int g = 0; g < 4; ++g) {
        acc0[g] = __builtin_amdgcn_mfma_f32_16x16x32_bf16(a0, wfrag[g][kk], acc0[g], 0, 0, 0);
        acc1[g] = __builtin_amdgcn_mfma_f32_16x16x32_bf16(a1, wfrag[g][kk], acc1[g], 0, 0, 0);
      }
    }
    // B: send the row-tile we don't keep (static branches: rule-#20 safe)
    if (!eh) {
      #pragma unroll
      for (int g = 0; g < 4; ++g)
        *(f32x4*)&EX[cg][g][l15][16 + lk * 4] = acc1[g];
    } else {
      #pragma unroll
      for (int g = 0; g < 4; ++g)
        *(f32x4*)&EX[cg][g][l15][lk * 4] = acc0[g];
    }
    __syncthreads();
    // C: combine halves, pointwise, h-write; e(t+1)
    f32x4 gacc[4];
    if (!eh) {
      #pragma unroll
      for (int g = 0; g < 4; ++g)
        gacc[g] = acc0[g] + *(const f32x4*)&EX[cg][g][l15][lk * 4];
    } else {
      #pragma unroll
      for (int g = 0; g < 4; ++g)
        gacc[g] = acc1[g] + *(const f32x4*)&EX[cg][g][l15][16 + lk * 4];
    }
    float hv[4];
    #pragma unroll
    for (int r = 0; r < 4; ++r) {
      float gi = sigm(gacc[0][r]);
      float gf = sigm(gacc[1][r]);
      float gg = tanh_(gacc[2][r]);
      float go = sigm(gacc[3][r]);
      float cc = gf * creg[r] + gi * gg;
      creg[r] = cc;
      float hh = go * tanh_(cc);
      hreg[r] = hh; hv[r] = hh;
    }
    {
      unsigned u01 = cvtpk(hv[0], hv[1]);
      unsigned u23 = cvtpk(hv[2], hv[3]);
      X[rowP + 0][wb + colX] = (short)(u01);
      X[rowP + 1][wb + colX] = (short)(u01 >> 16);
      X[rowP + 2][wb + colX] = (short)(u23);
      X[rowP + 3][wb + colX] = (short)(u23 >> 16);
    }
    if (t < T_STEPS - 1) do_e(t + 1);
    __syncthreads();
    // D: z = h_new @ W_out^T (waves 0 and 8; overlaps next step's phase A on others)
    if ((wave & 7) == 0) {
      const int rz = eh ? 16 : 0;
      f32x4 zac = {0.f, 0.f, 0.f, 0.f};
      #pragma unroll
      for (int kk = 0; kk < 4; ++kk) {
        s16x8 a  = *(const s16x8*)&X[rz + l15][wb + kk * 32 + lk * 8];
        s16x8 wz = *(const s16x8*)&WO[l15][kk * 32 + lk * 8];
        zac = __builtin_amdgcn_mfma_f32_16x16x32_bf16(a, wz, zac, 0, 0, 0);
      }
      if (l15 < 5) {
        #pragma unroll
        for (int r = 0; r < 4; ++r)
          outz[((size_t)(b0 + rz + lk * 4 + r) * T_STEPS + t) * 5 + l15] = zac[r];
      }
    }
  }

  // final h, c (fp32)
  #pragma unroll
  for (int r = 0; r < 4; ++r) {
    size_t base = (size_t)(b0 + rowP + r) * 128 + colX;
    hout[base] = hreg[r];
    cout[base] = creg[r];
  }
}

// -------- output BN: coalesced partial sums (atomics) + fused finalize/norm --------
__global__ void zsum_kernel(const float* __restrict__ z, float* __restrict__ st, int B) {
  int g = blockIdx.x * 256 + threadIdx.x;   // 40960 threads = 160 f4-cols x 256 row-groups
  int c = g % 160, rg = g / 160;
  float s[4] = {0.f, 0.f, 0.f, 0.f}, q[4] = {0.f, 0.f, 0.f, 0.f};
  for (int b = rg; b < B; b += 256) {
    float4 v = *(const float4*)(z + (size_t)b * 640 + c * 4);
    s[0] += v.x; q[0] += v.x * v.x;
    s[1] += v.y; q[1] += v.y * v.y;
    s[2] += v.z; q[2] += v.z * v.z;
    s[3] += v.w; q[3] += v.w * v.w;
  }
  #pragma unroll
  for (int k = 0; k < 4; ++k) {
    atomicAdd(&st[(c * 4 + k) * 2 + 0], s[k]);
    atomicAdd(&st[(c * 4 + k) * 2 + 1], q[k]);
  }
}

__global__ void norm_kernel(float* __restrict__ z, const float* __restrict__ st,
                            const float* __restrict__ gamma, const float* __restrict__ beta,
                            int n4, float invB) {
  int i = blockIdx.x * 256 + threadIdx.x;
  if (i >= n4) return;
  int c = i % 160;
  float4 v = *(const float4*)(z + (size_t)i * 4);
  float o[4] = {v.x, v.y, v.z, v.w};
  #pragma unroll
  for (int k = 0; k < 4; ++k) {
    int grp = c * 4 + k;
    int d = grp % 5;
    float S = st[grp * 2], Q = st[grp * 2 + 1];
    float mean = S * invB;
    float var  = Q * invB - mean * mean;
    float sc = gamma[d] * rsqrtf(var + BN_EPS);
    o[k] = o[k] * sc + (beta[d] - mean * sc);
  }
  float4 w = {o[0], o[1], o[2], o[3]};
  *(float4*)(z + (size_t)i * 4) = w;
}

extern "C" void kernel_launch(void* const* d_in, const int* in_sizes, int n_in,
                              void* d_out, int out_size, void* d_ws, size_t ws_size,
                              hipStream_t stream) {
  const float* inp    = (const float*)d_in[0];
  const float* W_emb  = (const float*)d_in[1];
  const float* b_emb  = (const float*)d_in[2];
  const float* g_emb  = (const float*)d_in[3];
  const float* be_emb = (const float*)d_in[4];
  const float* Wih    = (const float*)d_in[5];
  const float* bih    = (const float*)d_in[6];
  const float* Whh    = (const float*)d_in[7];
  const float* bhh    = (const float*)d_in[8];
  const float* Wout   = (const float*)d_in[9];
  // d_in[10] = b_out: cancels inside the output BatchNorm
  const float* g_out  = (const float*)d_in[11];
  const float* be_out = (const float*)d_in[12];

  const int B = in_sizes[0] / (2 * T_STEPS);   // 8192

  char* ws = (char*)d_ws;
  float*          cAp = (float*)(ws + 0);        // 64 KB
  float*          cBp = (float*)(ws + 65536);
  float*          cCp = (float*)(ws + 131072);
  unsigned short* Wb  = (unsigned short*)(ws + 196608);  // 256 KB bf16 [512][256]
  unsigned short* Wob = (unsigned short*)(ws + 458752);  // 4 KB bf16 [16][128]
  float*          st  = (float*)(ws + 462848);   // 1280 floats (sum,sumsq per t*5+d)

  float* outz = (float*)d_out;                   // [B][T][5] raw z, normalized in place
  float* hout = outz + (size_t)B * T_STEPS * 5;
  float* cout = hout + (size_t)B * 128;

  const float invB = 1.0f / (float)B;

  prep_e_kernel<<<T_STEPS, 256, 0, stream>>>(inp, W_emb, b_emb, g_emb, be_emb, cAp, cBp, cCp, B, invB);
  prepw_kernel<<<(512 * 256 + 16 * 128 + 255) / 256, 256, 0, stream>>>(Wih, Whh, Wout, Wb, Wob);
  hipMemsetAsync(st, 0, 1280 * sizeof(float), stream);
  lstm_kernel<<<B / 32, 1024, 0, stream>>>(inp, cAp, cBp, cCp, Wb, Wob, bih, bhh, outz, hout, cout);
  zsum_kernel<<<160, 256, 0, stream>>>(outz, st, B);
  const int n4 = B * (T_STEPS * 5) / 4;
  norm_kernel<<<(n4 + 255) / 256, 256, 0, stream>>>(outz, st, g_out, be_out, n4, invB);
}

// Round 5
// 596.175 us; speedup vs baseline: 1.1907x; 1.1907x over previous
//
#include <hip/hip_runtime.h>

typedef short s16x8 __attribute__((ext_vector_type(8)));
typedef float f32x4 __attribute__((ext_vector_type(4)));

#define T_STEPS 128
#define BN_EPS 1e-5f
#define LROW 392   // X row stride in shorts (384 + 8 pad; 196 dw % 32 = 4 -> conflict-free b128 reads)

__device__ __forceinline__ unsigned short f2bf(float f) {
  unsigned u = __float_as_uint(f);
  u += 0x7FFFu + ((u >> 16) & 1u);
  return (unsigned short)(u >> 16);
}
__device__ __forceinline__ unsigned cvtpk(float a, float b) {
  unsigned r;
  asm("v_cvt_pk_bf16_f32 %0, %1, %2" : "=v"(r) : "v"(a), "v"(b));
  return r;  // lo16 = bf16(a), hi16 = bf16(b)
}
__device__ __forceinline__ float sigm(float x) {
  return __builtin_amdgcn_rcpf(1.0f + __expf(-x));
}
__device__ __forceinline__ float tanh_(float x) {
  return 1.0f - 2.0f * __builtin_amdgcn_rcpf(1.0f + __expf(2.0f * x));
}

// ---------- fused: per-t input moments + embedding Linear/BN/ReLU fold ----------
__global__ void prep_e_kernel(const float* __restrict__ inp,
                              const float* __restrict__ W_emb, const float* __restrict__ b_emb,
                              const float* __restrict__ gamma, const float* __restrict__ beta,
                              float* __restrict__ cA, float* __restrict__ cB, float* __restrict__ cC,
                              int B, float invB) {
  int t = blockIdx.x, tid = threadIdx.x;
  float s0 = 0.f, s1 = 0.f, q0 = 0.f, q1 = 0.f, pp = 0.f;
  for (int b = tid; b < B; b += 256) {
    float2 x = *(const float2*)(inp + (size_t)b * (2 * T_STEPS) + 2 * t);
    s0 += x.x; s1 += x.y; q0 += x.x * x.x; q1 += x.y * x.y; pp += x.x * x.y;
  }
  float v[5] = {s0, s1, q0, q1, pp};
  #pragma unroll
  for (int i = 0; i < 5; ++i) {
    float x = v[i];
    #pragma unroll
    for (int o = 32; o > 0; o >>= 1) x += __shfl_down(x, o);
    v[i] = x;
  }
  __shared__ float red[4][5];
  __shared__ float tot[5];
  if ((tid & 63) == 0) {
    #pragma unroll
    for (int i = 0; i < 5; ++i) red[tid >> 6][i] = v[i];
  }
  __syncthreads();
  if (tid == 0) {
    #pragma unroll
    for (int i = 0; i < 5; ++i) tot[i] = red[0][i] + red[1][i] + red[2][i] + red[3][i];
  }
  __syncthreads();
  if (tid < 128) {
    int j = tid;
    float m0 = tot[0] * invB, m1 = tot[1] * invB;
    float q0m = tot[2] * invB, q1m = tot[3] * invB, p = tot[4] * invB;
    float v00 = q0m - m0 * m0, v11 = q1m - m1 * m1, v01 = p - m0 * m1;
    float w0 = W_emb[2 * j], w1 = W_emb[2 * j + 1];
    float mu  = w0 * m0 + w1 * m1 + b_emb[j];
    float var = w0 * w0 * v00 + w1 * w1 * v11 + 2.f * w0 * w1 * v01;
    float a = gamma[j] * rsqrtf(var + BN_EPS);
    int idx = t * 128 + j;
    cA[idx] = a * w0;
    cB[idx] = a * w1;
    cC[idx] = beta[j] + a * (b_emb[j] - mu);
  }
}

// ---------------- weights -> bf16 (gate concat + padded W_out) ----------------
__global__ void prepw_kernel(const float* __restrict__ Wih, const float* __restrict__ Whh,
                             const float* __restrict__ Wout,
                             unsigned short* __restrict__ Wb, unsigned short* __restrict__ Wob) {
  int idx = blockIdx.x * 256 + threadIdx.x;
  if (idx < 512 * 256) {
    int n = idx >> 8, k = idx & 255;
    float w = (k < 128) ? Wih[n * 128 + k] : Whh[n * 128 + (k - 128)];
    Wb[idx] = f2bf(w);
  } else if (idx < 512 * 256 + 16 * 128) {
    int i2 = idx - 512 * 256;
    int d = i2 >> 7, k = i2 & 127;
    Wob[i2] = (d < 5) ? f2bf(Wout[d * 128 + k]) : (unsigned short)0;
  }
}

// --------------------------- the recurrence ---------------------------------
// R2 structure, 16 rows/block: 512 thr (8 waves), grid = B/16 = 512 blocks ->
// 2 independent blocks/CU (desynchronized phases overlap MFMA with pointwise).
// Wave w owns gate-cols [16w,16w+16) of all 4 gates, full K=256 in registers.
// X cols: [0,128) e | [128,256) h0 | [256,384) h1.
__global__ __launch_bounds__(512, 2) void lstm_kernel(
    const float* __restrict__ inp,
    const float* __restrict__ cA, const float* __restrict__ cB, const float* __restrict__ cC,
    const unsigned short* __restrict__ Wb, const unsigned short* __restrict__ Wob,
    const float* __restrict__ bih, const float* __restrict__ bhh,
    float* __restrict__ outz, float* __restrict__ hout, float* __restrict__ cout) {
  __shared__ __align__(16) short X[16][LROW];   // 12544 B

  const int tid  = threadIdx.x;
  const int wave = tid >> 6;
  const int lane = tid & 63;
  const int l15  = lane & 15;
  const int lk   = lane >> 4;        // 0..3
  const int b0   = blockIdx.x * 16;
  const int em   = tid >> 5;         // e row 0..15
  const int ec4  = (tid & 31) * 4;   // e col (4-col group)

  // --- weights to registers (once). wave owns cols [16w,16w+16) of each gate.
  s16x8 wfrag[4][8];
  #pragma unroll
  for (int g = 0; g < 4; ++g)
    #pragma unroll
    for (int kk = 0; kk < 8; ++kk)
      wfrag[g][kk] = *(const s16x8*)(Wb + (size_t)(g * 128 + wave * 16 + l15) * 256 + kk * 32 + lk * 8);
  s16x8 wof[4];
  #pragma unroll
  for (int kk = 0; kk < 4; ++kk)
    wof[kk] = *(const s16x8*)(Wob + l15 * 128 + kk * 32 + lk * 8);
  float biasg[4];
  #pragma unroll
  for (int g = 0; g < 4; ++g) {
    int n = g * 128 + wave * 16 + l15;
    biasg[g] = bih[n] + bhh[n];
  }

  float creg[4] = {0.f, 0.f, 0.f, 0.f};
  float hreg[4] = {0.f, 0.f, 0.f, 0.f};
  const int colX = wave * 16 + l15;

  auto do_e = [&](int tn) {
    float2 xv = *(const float2*)(inp + (size_t)(b0 + em) * (2 * T_STEPS) + 2 * tn);
    float4 va = *(const float4*)(cA + tn * 128 + ec4);
    float4 vb = *(const float4*)(cB + tn * 128 + ec4);
    float4 vc = *(const float4*)(cC + tn * 128 + ec4);
    float e0 = fmaxf(0.f, vc.x + va.x * xv.x + vb.x * xv.y);
    float e1 = fmaxf(0.f, vc.y + va.y * xv.x + vb.y * xv.y);
    float e2 = fmaxf(0.f, vc.z + va.z * xv.x + vb.z * xv.y);
    float e3 = fmaxf(0.f, vc.w + va.w * xv.x + vb.w * xv.y);
    *(uint2*)&X[em][ec4] = make_uint2(cvtpk(e0, e1), cvtpk(e2, e3));
  };

  // init: zero h-buffer0, e(0)
  *(uint2*)&X[em][128 + ec4] = make_uint2(0u, 0u);
  do_e(0);
  __syncthreads();

  #pragma unroll 1
  for (int t = 0; t < T_STEPS; ++t) {
    const int rb = 128 + (t & 1) * 128;         // MFMA reads h from here
    const int wb = 128 + ((t + 1) & 1) * 128;   // update writes h here
    f32x4 acc[4];
    #pragma unroll
    for (int g = 0; g < 4; ++g) {
      f32x4 v = {biasg[g], biasg[g], biasg[g], biasg[g]};
      acc[g] = v;
    }
    #pragma unroll
    for (int kk = 0; kk < 8; ++kk) {
      const int coff = (kk < 4) ? (kk * 32 + lk * 8) : (rb + (kk - 4) * 32 + lk * 8);
      s16x8 a0 = *(const s16x8*)&X[l15][coff];
      #pragma unroll
      for (int g = 0; g < 4; ++g)
        acc[g] = __builtin_amdgcn_mfma_f32_16x16x32_bf16(a0, wfrag[g][kk], acc[g], 0, 0, 0);
    }
    // pointwise LSTM update; lane owns rows lk*4+r, col wave*16+l15
    float hv[4];
    #pragma unroll
    for (int r = 0; r < 4; ++r) {
      float gi = sigm(acc[0][r]);
      float gf = sigm(acc[1][r]);
      float gg = tanh_(acc[2][r]);
      float go = sigm(acc[3][r]);
      float cc = gf * creg[r] + gi * gg;
      creg[r] = cc;
      float hh = go * tanh_(cc);
      hreg[r] = hh; hv[r] = hh;
    }
    {
      unsigned u01 = cvtpk(hv[0], hv[1]);
      unsigned u23 = cvtpk(hv[2], hv[3]);
      X[lk * 4 + 0][wb + colX] = (short)(u01);
      X[lk * 4 + 1][wb + colX] = (short)(u01 >> 16);
      X[lk * 4 + 2][wb + colX] = (short)(u23);
      X[lk * 4 + 3][wb + colX] = (short)(u23 >> 16);
    }
    __syncthreads();
    // z = h_new @ W_out^T (wave 0 only; overlaps other waves' e-compute)
    if (wave == 0) {
      f32x4 zac = {0.f, 0.f, 0.f, 0.f};
      #pragma unroll
      for (int kk = 0; kk < 4; ++kk) {
        s16x8 a = *(const s16x8*)&X[l15][wb + kk * 32 + lk * 8];
        zac = __builtin_amdgcn_mfma_f32_16x16x32_bf16(a, wof[kk], zac, 0, 0, 0);
      }
      if (l15 < 5) {
        #pragma unroll
        for (int r = 0; r < 4; ++r)
          outz[((size_t)(b0 + lk * 4 + r) * T_STEPS + t) * 5 + l15] = zac[r];
      }
    }
    if (t < T_STEPS - 1) do_e(t + 1);
    __syncthreads();
  }

  // final h, c (fp32)
  #pragma unroll
  for (int r = 0; r < 4; ++r) {
    size_t base = (size_t)(b0 + lk * 4 + r) * 128 + colX;
    hout[base] = hreg[r];
    cout[base] = creg[r];
  }
}

// -------- output BN: coalesced partial sums (atomics) + fused finalize/norm --------
__global__ void zsum_kernel(const float* __restrict__ z, float* __restrict__ st, int B) {
  int g = blockIdx.x * 256 + threadIdx.x;   // 40960 threads = 160 f4-cols x 256 row-groups
  int c = g % 160, rg = g / 160;
  float s[4] = {0.f, 0.f, 0.f, 0.f}, q[4] = {0.f, 0.f, 0.f, 0.f};
  for (int b = rg; b < B; b += 256) {
    float4 v = *(const float4*)(z + (size_t)b * 640 + c * 4);
    s[0] += v.x; q[0] += v.x * v.x;
    s[1] += v.y; q[1] += v.y * v.y;
    s[2] += v.z; q[2] += v.z * v.z;
    s[3] += v.w; q[3] += v.w * v.w;
  }
  #pragma unroll
  for (int k = 0; k < 4; ++k) {
    atomicAdd(&st[(c * 4 + k) * 2 + 0], s[k]);
    atomicAdd(&st[(c * 4 + k) * 2 + 1], q[k]);
  }
}

__global__ void norm_kernel(float* __restrict__ z, const float* __restrict__ st,
                            const float* __restrict__ gamma, const float* __restrict__ beta,
                            int n4, float invB) {
  int i = blockIdx.x * 256 + threadIdx.x;
  if (i >= n4) return;
  int c = i % 160;
  float4 v = *(const float4*)(z + (size_t)i * 4);
  float o[4] = {v.x, v.y, v.z, v.w};
  #pragma unroll
  for (int k = 0; k < 4; ++k) {
    int grp = c * 4 + k;
    int d = grp % 5;
    float S = st[grp * 2], Q = st[grp * 2 + 1];
    float mean = S * invB;
    float var  = Q * invB - mean * mean;
    float sc = gamma[d] * rsqrtf(var + BN_EPS);
    o[k] = o[k] * sc + (beta[d] - mean * sc);
  }
  float4 w = {o[0], o[1], o[2], o[3]};
  *(float4*)(z + (size_t)i * 4) = w;
}

extern "C" void kernel_launch(void* const* d_in, const int* in_sizes, int n_in,
                              void* d_out, int out_size, void* d_ws, size_t ws_size,
                              hipStream_t stream) {
  const float* inp    = (const float*)d_in[0];
  const float* W_emb  = (const float*)d_in[1];
  const float* b_emb  = (const float*)d_in[2];
  const float* g_emb  = (const float*)d_in[3];
  const float* be_emb = (const float*)d_in[4];
  const float* Wih    = (const float*)d_in[5];
  const float* bih    = (const float*)d_in[6];
  const float* Whh    = (const float*)d_in[7];
  const float* bhh    = (const float*)d_in[8];
  const float* Wout   = (const float*)d_in[9];
  // d_in[10] = b_out: cancels inside the output BatchNorm
  const float* g_out  = (const float*)d_in[11];
  const float* be_out = (const float*)d_in[12];

  const int B = in_sizes[0] / (2 * T_STEPS);   // 8192

  char* ws = (char*)d_ws;
  float*          cAp = (float*)(ws + 0);        // 64 KB
  float*          cBp = (float*)(ws + 65536);
  float*          cCp = (float*)(ws + 131072);
  unsigned short* Wb  = (unsigned short*)(ws + 196608);  // 256 KB bf16 [512][256]
  unsigned short* Wob = (unsigned short*)(ws + 458752);  // 4 KB bf16 [16][128]
  float*          st  = (float*)(ws + 462848);   // 1280 floats (sum,sumsq per t*5+d)

  float* outz = (float*)d_out;                   // [B][T][5] raw z, normalized in place
  float* hout = outz + (size_t)B * T_STEPS * 5;
  float* cout = hout + (size_t)B * 128;

  const float invB = 1.0f / (float)B;

  prep_e_kernel<<<T_STEPS, 256, 0, stream>>>(inp, W_emb, b_emb, g_emb, be_emb, cAp, cBp, cCp, B, invB);
  prepw_kernel<<<(512 * 256 + 16 * 128 + 255) / 256, 256, 0, stream>>>(Wih, Whh, Wout, Wb, Wob);
  hipMemsetAsync(st, 0, 1280 * sizeof(float), stream);
  lstm_kernel<<<B / 16, 512, 0, stream>>>(inp, cAp, cBp, cCp, Wb, Wob, bih, bhh, outz, hout, cout);
  zsum_kernel<<<160, 256, 0, stream>>>(outz, st, B);
  const int n4 = B * (T_STEPS * 5) / 4;
  norm_kernel<<<(n4 + 255) / 256, 256, 0, stream>>>(outz, st, g_out, be_out, n4, invB);
}

// Round 6
// 551.229 us; speedup vs baseline: 1.2878x; 1.0815x over previous
//
#include <hip/hip_runtime.h>

typedef short s16x8 __attribute__((ext_vector_type(8)));
typedef float f32x4 __attribute__((ext_vector_type(4)));

#define T_STEPS 128
#define BN_EPS 1e-5f
#define LROW 392   // X row stride in shorts (384 + 8 pad; 196 dw % 32 = 4 -> conflict-free b128)
#define LOG2E 1.4426950408889634f

__device__ __forceinline__ unsigned short f2bf(float f) {
  unsigned u = __float_as_uint(f);
  u += 0x7FFFu + ((u >> 16) & 1u);
  return (unsigned short)(u >> 16);
}
__device__ __forceinline__ unsigned cvtpk(float a, float b) {
  unsigned r;
  asm("v_cvt_pk_bf16_f32 %0, %1, %2" : "=v"(r) : "v"(a), "v"(b));
  return r;  // lo16 = bf16(a), hi16 = bf16(b)
}
// sigmoid via raw v_exp_f32 (exp2): mul + exp + add + rcp
__device__ __forceinline__ float sigm(float x) {
  return __builtin_amdgcn_rcpf(1.0f + __builtin_amdgcn_exp2f(x * -LOG2E));
}
// tanh(y) = 1 - 2/(1+exp2(2*log2e*y)): mul + exp + add + rcp + fma
__device__ __forceinline__ float tanh_(float x) {
  float r = __builtin_amdgcn_rcpf(1.0f + __builtin_amdgcn_exp2f(x * (2.0f * LOG2E)));
  return fmaf(-2.0f, r, 1.0f);
}

// ---------- fused: per-t input moments + embedding Linear/BN/ReLU fold ----------
__global__ void prep_e_kernel(const float* __restrict__ inp,
                              const float* __restrict__ W_emb, const float* __restrict__ b_emb,
                              const float* __restrict__ gamma, const float* __restrict__ beta,
                              float* __restrict__ cA, float* __restrict__ cB, float* __restrict__ cC,
                              int B, float invB) {
  int t = blockIdx.x, tid = threadIdx.x;
  float s0 = 0.f, s1 = 0.f, q0 = 0.f, q1 = 0.f, pp = 0.f;
  for (int b = tid; b < B; b += 256) {
    float2 x = *(const float2*)(inp + (size_t)b * (2 * T_STEPS) + 2 * t);
    s0 += x.x; s1 += x.y; q0 += x.x * x.x; q1 += x.y * x.y; pp += x.x * x.y;
  }
  float v[5] = {s0, s1, q0, q1, pp};
  #pragma unroll
  for (int i = 0; i < 5; ++i) {
    float x = v[i];
    #pragma unroll
    for (int o = 32; o > 0; o >>= 1) x += __shfl_down(x, o);
    v[i] = x;
  }
  __shared__ float red[4][5];
  __shared__ float tot[5];
  if ((tid & 63) == 0) {
    #pragma unroll
    for (int i = 0; i < 5; ++i) red[tid >> 6][i] = v[i];
  }
  __syncthreads();
  if (tid == 0) {
    #pragma unroll
    for (int i = 0; i < 5; ++i) tot[i] = red[0][i] + red[1][i] + red[2][i] + red[3][i];
  }
  __syncthreads();
  if (tid < 128) {
    int j = tid;
    float m0 = tot[0] * invB, m1 = tot[1] * invB;
    float q0m = tot[2] * invB, q1m = tot[3] * invB, p = tot[4] * invB;
    float v00 = q0m - m0 * m0, v11 = q1m - m1 * m1, v01 = p - m0 * m1;
    float w0 = W_emb[2 * j], w1 = W_emb[2 * j + 1];
    float mu  = w0 * m0 + w1 * m1 + b_emb[j];
    float var = w0 * w0 * v00 + w1 * w1 * v11 + 2.f * w0 * w1 * v01;
    float a = gamma[j] * rsqrtf(var + BN_EPS);
    int idx = t * 128 + j;
    cA[idx] = a * w0;
    cB[idx] = a * w1;
    cC[idx] = beta[j] + a * (b_emb[j] - mu);
  }
}

// ---------------- weights -> bf16 (gate concat + padded W_out) ----------------
__global__ void prepw_kernel(const float* __restrict__ Wih, const float* __restrict__ Whh,
                             const float* __restrict__ Wout,
                             unsigned short* __restrict__ Wb, unsigned short* __restrict__ Wob) {
  int idx = blockIdx.x * 256 + threadIdx.x;
  if (idx < 512 * 256) {
    int n = idx >> 8, k = idx & 255;
    float w = (k < 128) ? Wih[n * 128 + k] : Whh[n * 128 + (k - 128)];
    Wb[idx] = f2bf(w);
  } else if (idx < 512 * 256 + 16 * 128) {
    int i2 = idx - 512 * 256;
    int d = i2 >> 7, k = i2 & 127;
    Wob[i2] = (d < 5) ? f2bf(Wout[d * 128 + k]) : (unsigned short)0;
  }
}

// --------------------------- the recurrence ---------------------------------
// R2 structure (best known): 512 thr (8 waves), 32 batch rows/block, grid 256.
// Wave w owns gate-cols [16w,16w+16) of all 4 gates, full K=256 in registers.
// X cols: [0,128) e | [128,256) h0 | [256,384) h1.
__global__ __launch_bounds__(512, 2) void lstm_kernel(
    const float* __restrict__ inp,
    const float* __restrict__ cA, const float* __restrict__ cB, const float* __restrict__ cC,
    const unsigned short* __restrict__ Wb, const unsigned short* __restrict__ Wob,
    const float* __restrict__ bih, const float* __restrict__ bhh,
    float* __restrict__ outz, float* __restrict__ hout, float* __restrict__ cout) {
  __shared__ __align__(16) short X[32][LROW];   // 25088 B

  const int tid  = threadIdx.x;
  const int wave = tid >> 6;
  const int lane = tid & 63;
  const int l15  = lane & 15;
  const int lk   = lane >> 4;        // 0..3
  const int b0   = blockIdx.x * 32;
  const int em   = tid >> 4;         // e row 0..31
  const int ec8  = (tid & 15) * 8;   // e col (8-col group)

  // --- weights to registers (once). wave owns cols [16w,16w+16) of each gate.
  s16x8 wfrag[4][8];
  #pragma unroll
  for (int g = 0; g < 4; ++g)
    #pragma unroll
    for (int kk = 0; kk < 8; ++kk)
      wfrag[g][kk] = *(const s16x8*)(Wb + (size_t)(g * 128 + wave * 16 + l15) * 256 + kk * 32 + lk * 8);
  s16x8 wof[4];
  #pragma unroll
  for (int kk = 0; kk < 4; ++kk)
    wof[kk] = *(const s16x8*)(Wob + l15 * 128 + kk * 32 + lk * 8);
  float biasg[4];
  #pragma unroll
  for (int g = 0; g < 4; ++g) {
    int n = g * 128 + wave * 16 + l15;
    biasg[g] = bih[n] + bhh[n];
  }

  float creg[2][4] = {{0.f,0.f,0.f,0.f},{0.f,0.f,0.f,0.f}};
  float hreg[2][4] = {{0.f,0.f,0.f,0.f},{0.f,0.f,0.f,0.f}};

  auto do_e = [&](int tn) {
    float2 xv = *(const float2*)(inp + (size_t)(b0 + em) * (2 * T_STEPS) + 2 * tn);
    const float4* pa = (const float4*)(cA + tn * 128 + ec8);
    const float4* pb = (const float4*)(cB + tn * 128 + ec8);
    const float4* pc = (const float4*)(cC + tn * 128 + ec8);
    unsigned w[4];
    #pragma unroll
    for (int q = 0; q < 2; ++q) {
      float4 va = pa[q], vb = pb[q], vc = pc[q];
      float e0 = fmaxf(0.f, vc.x + va.x * xv.x + vb.x * xv.y);
      float e1 = fmaxf(0.f, vc.y + va.y * xv.x + vb.y * xv.y);
      float e2 = fmaxf(0.f, vc.z + va.z * xv.x + vb.z * xv.y);
      float e3 = fmaxf(0.f, vc.w + va.w * xv.x + vb.w * xv.y);
      w[2 * q]     = cvtpk(e0, e1);
      w[2 * q + 1] = cvtpk(e2, e3);
    }
    *(uint4*)&X[em][ec8] = make_uint4(w[0], w[1], w[2], w[3]);
  };

  // init: zero h-buffer0, e(0)
  *(uint4*)&X[em][128 + ec8] = make_uint4(0u, 0u, 0u, 0u);
  do_e(0);
  __syncthreads();

  #pragma unroll 1
  for (int t = 0; t < T_STEPS; ++t) {
    const int rb = 128 + (t & 1) * 128;         // MFMA reads h from here
    const int wb = 128 + ((t + 1) & 1) * 128;   // update writes h here
    f32x4 acc[2][4];
    #pragma unroll
    for (int mf = 0; mf < 2; ++mf)
      #pragma unroll
      for (int g = 0; g < 4; ++g) {
        f32x4 v = {biasg[g], biasg[g], biasg[g], biasg[g]};
        acc[mf][g] = v;
      }
    #pragma unroll
    for (int kk = 0; kk < 8; ++kk) {
      const int coff = (kk < 4) ? (kk * 32 + lk * 8) : (rb + (kk - 4) * 32 + lk * 8);
      s16x8 a0 = *(const s16x8*)&X[l15][coff];
      s16x8 a1 = *(const s16x8*)&X[16 + l15][coff];
      #pragma unroll
      for (int g = 0; g < 4; ++g) {
        acc[0][g] = __builtin_amdgcn_mfma_f32_16x16x32_bf16(a0, wfrag[g][kk], acc[0][g], 0, 0, 0);
        acc[1][g] = __builtin_amdgcn_mfma_f32_16x16x32_bf16(a1, wfrag[g][kk], acc[1][g], 0, 0, 0);
      }
    }
    // pointwise LSTM update; lane owns rows {lk*4+r, +16}, col wave*16+l15
    #pragma unroll
    for (int mf = 0; mf < 2; ++mf) {
      float hv[4];
      #pragma unroll
      for (int r = 0; r < 4; ++r) {
        float gi = sigm(acc[mf][0][r]);
        float gf = sigm(acc[mf][1][r]);
        float gg = tanh_(acc[mf][2][r]);
        float go = sigm(acc[mf][3][r]);
        float cc = fmaf(gf, creg[mf][r], gi * gg);
        creg[mf][r] = cc;
        float hh = go * tanh_(cc);
        hreg[mf][r] = hh; hv[r] = hh;
      }
      unsigned u01 = cvtpk(hv[0], hv[1]);
      unsigned u23 = cvtpk(hv[2], hv[3]);
      const int rp = mf * 16 + lk * 4;
      const int cw = wb + wave * 16 + l15;
      X[rp + 0][cw] = (short)(u01);
      X[rp + 1][cw] = (short)(u01 >> 16);
      X[rp + 2][cw] = (short)(u23);
      X[rp + 3][cw] = (short)(u23 >> 16);
    }
    __syncthreads();
    // z = h_new @ W_out^T  (waves 0,1; 16 rows each; overlaps others' e-compute)
    if (wave < 2) {
      f32x4 zac = {0.f, 0.f, 0.f, 0.f};
      #pragma unroll
      for (int kk = 0; kk < 4; ++kk) {
        s16x8 a = *(const s16x8*)&X[wave * 16 + l15][wb + kk * 32 + lk * 8];
        zac = __builtin_amdgcn_mfma_f32_16x16x32_bf16(a, wof[kk], zac, 0, 0, 0);
      }
      if (l15 < 5) {
        #pragma unroll
        for (int r = 0; r < 4; ++r) {
          int m = wave * 16 + lk * 4 + r;
          outz[((size_t)(b0 + m) * T_STEPS + t) * 5 + l15] = zac[r];
        }
      }
    }
    if (t < T_STEPS - 1) do_e(t + 1);
    __syncthreads();
  }

  // final h, c (fp32)
  #pragma unroll
  for (int mf = 0; mf < 2; ++mf)
    #pragma unroll
    for (int r = 0; r < 4; ++r) {
      int m = mf * 16 + lk * 4 + r;
      size_t base = (size_t)(b0 + m) * 128 + wave * 16 + l15;
      hout[base] = hreg[mf][r];
      cout[base] = creg[mf][r];
    }
}

// -------- output BN: coalesced partial sums (atomics) + fused finalize/norm --------
__global__ void zsum_kernel(const float* __restrict__ z, float* __restrict__ st, int B) {
  int g = blockIdx.x * 256 + threadIdx.x;   // 81920 threads = 160 f4-cols x 512 row-groups
  int c = g % 160, rg = g / 160;
  float s[4] = {0.f, 0.f, 0.f, 0.f}, q[4] = {0.f, 0.f, 0.f, 0.f};
  for (int b = rg; b < B; b += 512) {
    float4 v = *(const float4*)(z + (size_t)b * 640 + c * 4);
    s[0] += v.x; q[0] += v.x * v.x;
    s[1] += v.y; q[1] += v.y * v.y;
    s[2] += v.z; q[2] += v.z * v.z;
    s[3] += v.w; q[3] += v.w * v.w;
  }
  #pragma unroll
  for (int k = 0; k < 4; ++k) {
    atomicAdd(&st[(c * 4 + k) * 2 + 0], s[k]);
    atomicAdd(&st[(c * 4 + k) * 2 + 1], q[k]);
  }
}

__global__ void norm_kernel(float* __restrict__ z, const float* __restrict__ st,
                            const float* __restrict__ gamma, const float* __restrict__ beta,
                            int n4, float invB) {
  int i = blockIdx.x * 256 + threadIdx.x;
  if (i >= n4) return;
  int c = i % 160;
  float4 v = *(const float4*)(z + (size_t)i * 4);
  float o[4] = {v.x, v.y, v.z, v.w};
  #pragma unroll
  for (int k = 0; k < 4; ++k) {
    int grp = c * 4 + k;
    int d = grp % 5;
    float S = st[grp * 2], Q = st[grp * 2 + 1];
    float mean = S * invB;
    float var  = Q * invB - mean * mean;
    float sc = gamma[d] * rsqrtf(var + BN_EPS);
    o[k] = o[k] * sc + (beta[d] - mean * sc);
  }
  float4 w = {o[0], o[1], o[2], o[3]};
  *(float4*)(z + (size_t)i * 4) = w;
}

extern "C" void kernel_launch(void* const* d_in, const int* in_sizes, int n_in,
                              void* d_out, int out_size, void* d_ws, size_t ws_size,
                              hipStream_t stream) {
  const float* inp    = (const float*)d_in[0];
  const float* W_emb  = (const float*)d_in[1];
  const float* b_emb  = (const float*)d_in[2];
  const float* g_emb  = (const float*)d_in[3];
  const float* be_emb = (const float*)d_in[4];
  const float* Wih    = (const float*)d_in[5];
  const float* bih    = (const float*)d_in[6];
  const float* Whh    = (const float*)d_in[7];
  const float* bhh    = (const float*)d_in[8];
  const float* Wout   = (const float*)d_in[9];
  // d_in[10] = b_out: cancels inside the output BatchNorm
  const float* g_out  = (const float*)d_in[11];
  const float* be_out = (const float*)d_in[12];

  const int B = in_sizes[0] / (2 * T_STEPS);   // 8192

  char* ws = (char*)d_ws;
  float*          cAp = (float*)(ws + 0);        // 64 KB
  float*          cBp = (float*)(ws + 65536);
  float*          cCp = (float*)(ws + 131072);
  unsigned short* Wb  = (unsigned short*)(ws + 196608);  // 256 KB bf16 [512][256]
  unsigned short* Wob = (unsigned short*)(ws + 458752);  // 4 KB bf16 [16][128]
  float*          st  = (float*)(ws + 462848);   // 1280 floats (sum,sumsq per t*5+d)

  float* outz = (float*)d_out;                   // [B][T][5] raw z, normalized in place
  float* hout = outz + (size_t)B * T_STEPS * 5;
  float* cout = hout + (size_t)B * 128;

  const float invB = 1.0f / (float)B;

  prep_e_kernel<<<T_STEPS, 256, 0, stream>>>(inp, W_emb, b_emb, g_emb, be_emb, cAp, cBp, cCp, B, invB);
  prepw_kernel<<<(512 * 256 + 16 * 128 + 255) / 256, 256, 0, stream>>>(Wih, Whh, Wout, Wb, Wob);
  hipMemsetAsync(st, 0, 1280 * sizeof(float), stream);
  lstm_kernel<<<B / 32, 512, 0, stream>>>(inp, cAp, cBp, cCp, Wb, Wob, bih, bhh, outz, hout, cout);
  zsum_kernel<<<320, 256, 0, stream>>>(outz, st, B);
  const int n4 = B * (T_STEPS * 5) / 4;
  norm_kernel<<<(n4 + 255) / 256, 256, 0, stream>>>(outz, st, g_out, be_out, n4, invB);
}

// Round 7
// 522.615 us; speedup vs baseline: 1.3583x; 1.0548x over previous
//
#include <hip/hip_runtime.h>

typedef short s16x8 __attribute__((ext_vector_type(8)));
typedef float f32x4 __attribute__((ext_vector_type(4)));

#define T_STEPS 128
#define BN_EPS 1e-5f
#define LROW 264   // X row stride in shorts (256 + 8 pad; 132 dw % 32 = 4 -> conflict-free b128)
#define LOG2E 1.4426950408889634f

__device__ __forceinline__ unsigned short f2bf(float f) {
  unsigned u = __float_as_uint(f);
  u += 0x7FFFu + ((u >> 16) & 1u);
  return (unsigned short)(u >> 16);
}
__device__ __forceinline__ unsigned cvtpk(float a, float b) {
  unsigned r;
  asm("v_cvt_pk_bf16_f32 %0, %1, %2" : "=v"(r) : "v"(a), "v"(b));
  return r;  // lo16 = bf16(a), hi16 = bf16(b)
}
__device__ __forceinline__ float sigm(float x) {
  return __builtin_amdgcn_rcpf(1.0f + __builtin_amdgcn_exp2f(x * -LOG2E));
}
__device__ __forceinline__ float tanh_(float x) {
  float r = __builtin_amdgcn_rcpf(1.0f + __builtin_amdgcn_exp2f(x * (2.0f * LOG2E)));
  return fmaf(-2.0f, r, 1.0f);
}

// ---------- fused: per-t input moments + embedding Linear/BN/ReLU fold ----------
__global__ void prep_e_kernel(const float* __restrict__ inp,
                              const float* __restrict__ W_emb, const float* __restrict__ b_emb,
                              const float* __restrict__ gamma, const float* __restrict__ beta,
                              float* __restrict__ cA, float* __restrict__ cB, float* __restrict__ cC,
                              int B, float invB) {
  int t = blockIdx.x, tid = threadIdx.x;
  float s0 = 0.f, s1 = 0.f, q0 = 0.f, q1 = 0.f, pp = 0.f;
  for (int b = tid; b < B; b += 256) {
    float2 x = *(const float2*)(inp + (size_t)b * (2 * T_STEPS) + 2 * t);
    s0 += x.x; s1 += x.y; q0 += x.x * x.x; q1 += x.y * x.y; pp += x.x * x.y;
  }
  float v[5] = {s0, s1, q0, q1, pp};
  #pragma unroll
  for (int i = 0; i < 5; ++i) {
    float x = v[i];
    #pragma unroll
    for (int o = 32; o > 0; o >>= 1) x += __shfl_down(x, o);
    v[i] = x;
  }
  __shared__ float red[4][5];
  __shared__ float tot[5];
  if ((tid & 63) == 0) {
    #pragma unroll
    for (int i = 0; i < 5; ++i) red[tid >> 6][i] = v[i];
  }
  __syncthreads();
  if (tid == 0) {
    #pragma unroll
    for (int i = 0; i < 5; ++i) tot[i] = red[0][i] + red[1][i] + red[2][i] + red[3][i];
  }
  __syncthreads();
  if (tid < 128) {
    int j = tid;
    float m0 = tot[0] * invB, m1 = tot[1] * invB;
    float q0m = tot[2] * invB, q1m = tot[3] * invB, p = tot[4] * invB;
    float v00 = q0m - m0 * m0, v11 = q1m - m1 * m1, v01 = p - m0 * m1;
    float w0 = W_emb[2 * j], w1 = W_emb[2 * j + 1];
    float mu  = w0 * m0 + w1 * m1 + b_emb[j];
    float var = w0 * w0 * v00 + w1 * w1 * v11 + 2.f * w0 * w1 * v01;
    float a = gamma[j] * rsqrtf(var + BN_EPS);
    int idx = t * 128 + j;
    cA[idx] = a * w0;
    cB[idx] = a * w1;
    cC[idx] = beta[j] + a * (b_emb[j] - mu);
  }
}

// ---------------- weights -> bf16 (gate concat + padded W_out) ----------------
__global__ void prepw_kernel(const float* __restrict__ Wih, const float* __restrict__ Whh,
                             const float* __restrict__ Wout,
                             unsigned short* __restrict__ Wb, unsigned short* __restrict__ Wob) {
  int idx = blockIdx.x * 256 + threadIdx.x;
  if (idx < 512 * 256) {
    int n = idx >> 8, k = idx & 255;
    float w = (k < 128) ? Wih[n * 128 + k] : Whh[n * 128 + (k - 128)];
    Wb[idx] = f2bf(w);
  } else if (idx < 512 * 256 + 16 * 128) {
    int i2 = idx - 512 * 256;
    int d = i2 >> 7, k = i2 & 127;
    Wob[i2] = (d < 5) ? f2bf(Wout[d * 128 + k]) : (unsigned short)0;
  }
}

// --------------------------- the recurrence ---------------------------------
// 512 thr (8 waves), 32 rows/block as 2 INDEPENDENT 16-row groups, staggered:
// even phase: MFMA(g0,t) || pointwise(g1,t-1) || z(g0,t-1) || e-write(g1,t)
// odd  phase: MFMA(g1,t) || pointwise(g0,t)   || z(g1,t-1) || e-write(g0,t+1)
// Pointwise consumes the PREVIOUS phase's accumulators -> no intra-phase dep.
// X rows: u*16+r; cols [0,128) e | [128,256) h (single buffer, barrier-safe).
__global__ __launch_bounds__(512, 2) void lstm_kernel(
    const float* __restrict__ inp,
    const float* __restrict__ cA, const float* __restrict__ cB, const float* __restrict__ cC,
    const unsigned short* __restrict__ Wb, const unsigned short* __restrict__ Wob,
    const float* __restrict__ bih, const float* __restrict__ bhh,
    float* __restrict__ outz, float* __restrict__ st,
    float* __restrict__ hout, float* __restrict__ cout) {
  __shared__ __align__(16) short X[32][LROW];   // 16896 B

  const int tid  = threadIdx.x;
  const int wave = tid >> 6;
  const int lane = tid & 63;
  const int l15  = lane & 15;
  const int lk   = lane >> 4;        // 0..3
  const int b0   = blockIdx.x * 32;

  // --- weights to registers (once). wave owns cols [16w,16w+16) of each gate.
  s16x8 wfrag[4][8];
  #pragma unroll
  for (int g = 0; g < 4; ++g)
    #pragma unroll
    for (int kk = 0; kk < 8; ++kk)
      wfrag[g][kk] = *(const s16x8*)(Wb + (size_t)(g * 128 + wave * 16 + l15) * 256 + kk * 32 + lk * 8);
  s16x8 wof[4];
  #pragma unroll
  for (int kk = 0; kk < 4; ++kk)
    wof[kk] = *(const s16x8*)(Wob + l15 * 128 + kk * 32 + lk * 8);
  float biasg[4];
  #pragma unroll
  for (int g = 0; g < 4; ++g) {
    int n = g * 128 + wave * 16 + l15;
    biasg[g] = bih[n] + bhh[n];
  }

  float creg[2][4] = {{0.f,0.f,0.f,0.f},{0.f,0.f,0.f,0.f}};
  float hreg[2][4] = {{0.f,0.f,0.f,0.f},{0.f,0.f,0.f,0.f}};

  // e-writer: group u, time tn. 16 rows x 128 cols / 512 thr = 4 elems/thread.
  auto do_e = [&](int u, int tn) {
    int row = (tid >> 5);               // 0..15
    int c4  = (tid & 31) * 4;
    float2 xv = *(const float2*)(inp + (size_t)(b0 + u * 16 + row) * (2 * T_STEPS) + 2 * tn);
    float4 va = *(const float4*)(cA + tn * 128 + c4);
    float4 vb = *(const float4*)(cB + tn * 128 + c4);
    float4 vc = *(const float4*)(cC + tn * 128 + c4);
    float e0 = fmaxf(0.f, vc.x + va.x * xv.x + vb.x * xv.y);
    float e1 = fmaxf(0.f, vc.y + va.y * xv.x + vb.y * xv.y);
    float e2 = fmaxf(0.f, vc.z + va.z * xv.x + vb.z * xv.y);
    float e3 = fmaxf(0.f, vc.w + va.w * xv.x + vb.w * xv.y);
    *(uint2*)&X[u * 16 + row][c4] = make_uint2(cvtpk(e0, e1), cvtpk(e2, e3));
  };

  // gate MFMAs for group u -> ac[0..3]
  auto G = [&](int u, f32x4* ac) {
    #pragma unroll
    for (int g = 0; g < 4; ++g) {
      f32x4 v = {biasg[g], biasg[g], biasg[g], biasg[g]};
      ac[g] = v;
    }
    #pragma unroll
    for (int kk = 0; kk < 8; ++kk) {
      const int coff = (kk < 4) ? (kk * 32 + lk * 8) : (128 + (kk - 4) * 32 + lk * 8);
      s16x8 a = *(const s16x8*)&X[u * 16 + l15][coff];
      #pragma unroll
      for (int g = 0; g < 4; ++g)
        ac[g] = __builtin_amdgcn_mfma_f32_16x16x32_bf16(a, wfrag[g][kk], ac[g], 0, 0, 0);
    }
  };

  // pointwise + h-write for group u (consumes prev-phase ac)
  auto P = [&](int u, const f32x4* ac) {
    float hv[4];
    #pragma unroll
    for (int r = 0; r < 4; ++r) {
      float gi = sigm(ac[0][r]);
      float gf = sigm(ac[1][r]);
      float gg = tanh_(ac[2][r]);
      float go = sigm(ac[3][r]);
      float cc = fmaf(gf, creg[u][r], gi * gg);
      creg[u][r] = cc;
      float hh = go * tanh_(cc);
      hreg[u][r] = hh; hv[r] = hh;
    }
    unsigned u01 = cvtpk(hv[0], hv[1]);
    unsigned u23 = cvtpk(hv[2], hv[3]);
    const int rp = u * 16 + lk * 4;
    const int cw = 128 + wave * 16 + l15;
    X[rp + 0][cw] = (short)(u01);
    X[rp + 1][cw] = (short)(u01 >> 16);
    X[rp + 2][cw] = (short)(u23);
    X[rp + 3][cw] = (short)(u23 >> 16);
  };

  // z = h @ W_out^T for group u at time tn (ONE wave calls this) + fused BN stats
  auto do_z = [&](int u, int tn) {
    f32x4 zac = {0.f, 0.f, 0.f, 0.f};
    #pragma unroll
    for (int kk = 0; kk < 4; ++kk) {
      s16x8 a = *(const s16x8*)&X[u * 16 + l15][128 + kk * 32 + lk * 8];
      zac = __builtin_amdgcn_mfma_f32_16x16x32_bf16(a, wof[kk], zac, 0, 0, 0);
    }
    float s = zac[0] + zac[1] + zac[2] + zac[3];
    float q = zac[0]*zac[0] + zac[1]*zac[1] + zac[2]*zac[2] + zac[3]*zac[3];
    s += __shfl_xor(s, 16); s += __shfl_xor(s, 32);
    q += __shfl_xor(q, 16); q += __shfl_xor(q, 32);
    if (l15 < 5) {
      #pragma unroll
      for (int r = 0; r < 4; ++r)
        outz[((size_t)(b0 + u * 16 + lk * 4 + r) * T_STEPS + tn) * 5 + l15] = zac[r];
      if (lk == 0) {
        atomicAdd(&st[(tn * 5 + l15) * 2 + 0], s);
        atomicAdd(&st[(tn * 5 + l15) * 2 + 1], q);
      }
    }
  };

  // init: zero both groups' h, write e0(0)
  {
    int row = tid >> 4, c8 = (tid & 15) * 8;
    *(uint4*)&X[row][128 + c8] = make_uint4(0u, 0u, 0u, 0u);
  }
  do_e(0, 0);
  __syncthreads();

  f32x4 acc0[4], acc1[4];

  #pragma unroll 1
  for (int m = 0; m < T_STEPS; ++m) {
    // ---- even phase: G0(m) || P1(m-1) || z0(m-1) || e1(m)
    G(0, acc0);
    do_e(1, m);
    if (m > 0) {
      P(1, acc1);
      if (wave == 0) do_z(0, m - 1);
    }
    __syncthreads();
    // ---- odd phase: G1(m) || P0(m) || z1(m-1) || e0(m+1)
    G(1, acc1);
    if (m < T_STEPS - 1) do_e(0, m + 1);
    P(0, acc0);
    if (m > 0 && wave == 1) do_z(1, m - 1);
    __syncthreads();
  }
  // tail: P1(127), z0(127); barrier; z1(127)
  P(1, acc1);
  if (wave == 0) do_z(0, T_STEPS - 1);
  __syncthreads();
  if (wave == 1) do_z(1, T_STEPS - 1);

  // final h, c (fp32)
  #pragma unroll
  for (int u = 0; u < 2; ++u)
    #pragma unroll
    for (int r = 0; r < 4; ++r) {
      int mrow = u * 16 + lk * 4 + r;
      size_t base = (size_t)(b0 + mrow) * 128 + wave * 16 + l15;
      hout[base] = hreg[u][r];
      cout[base] = creg[u][r];
    }
}

// -------- output BN normalize (stats accumulated inside lstm via atomics) --------
__global__ void norm_kernel(float* __restrict__ z, const float* __restrict__ st,
                            const float* __restrict__ gamma, const float* __restrict__ beta,
                            int n4, float invB) {
  int i = blockIdx.x * 256 + threadIdx.x;
  if (i >= n4) return;
  int c = i % 160;
  float4 v = *(const float4*)(z + (size_t)i * 4);
  float o[4] = {v.x, v.y, v.z, v.w};
  #pragma unroll
  for (int k = 0; k < 4; ++k) {
    int grp = c * 4 + k;
    int d = grp % 5;
    float S = st[grp * 2], Q = st[grp * 2 + 1];
    float mean = S * invB;
    float var  = Q * invB - mean * mean;
    float sc = gamma[d] * rsqrtf(var + BN_EPS);
    o[k] = o[k] * sc + (beta[d] - mean * sc);
  }
  float4 w = {o[0], o[1], o[2], o[3]};
  *(float4*)(z + (size_t)i * 4) = w;
}

extern "C" void kernel_launch(void* const* d_in, const int* in_sizes, int n_in,
                              void* d_out, int out_size, void* d_ws, size_t ws_size,
                              hipStream_t stream) {
  const float* inp    = (const float*)d_in[0];
  const float* W_emb  = (const float*)d_in[1];
  const float* b_emb  = (const float*)d_in[2];
  const float* g_emb  = (const float*)d_in[3];
  const float* be_emb = (const float*)d_in[4];
  const float* Wih    = (const float*)d_in[5];
  const float* bih    = (const float*)d_in[6];
  const float* Whh    = (const float*)d_in[7];
  const float* bhh    = (const float*)d_in[8];
  const float* Wout   = (const float*)d_in[9];
  // d_in[10] = b_out: cancels inside the output BatchNorm
  const float* g_out  = (const float*)d_in[11];
  const float* be_out = (const float*)d_in[12];

  const int B = in_sizes[0] / (2 * T_STEPS);   // 8192

  char* ws = (char*)d_ws;
  float*          cAp = (float*)(ws + 0);        // 64 KB
  float*          cBp = (float*)(ws + 65536);
  float*          cCp = (float*)(ws + 131072);
  unsigned short* Wb  = (unsigned short*)(ws + 196608);  // 256 KB bf16 [512][256]
  unsigned short* Wob = (unsigned short*)(ws + 458752);  // 4 KB bf16 [16][128]
  float*          st  = (float*)(ws + 462848);   // 1280 floats (sum,sumsq per t*5+d)

  float* outz = (float*)d_out;                   // [B][T][5] raw z, normalized in place
  float* hout = outz + (size_t)B * T_STEPS * 5;
  float* cout = hout + (size_t)B * 128;

  const float invB = 1.0f / (float)B;

  prep_e_kernel<<<T_STEPS, 256, 0, stream>>>(inp, W_emb, b_emb, g_emb, be_emb, cAp, cBp, cCp, B, invB);
  prepw_kernel<<<(512 * 256 + 16 * 128 + 255) / 256, 256, 0, stream>>>(Wih, Whh, Wout, Wb, Wob);
  hipMemsetAsync(st, 0, 1280 * sizeof(float), stream);
  lstm_kernel<<<B / 32, 512, 0, stream>>>(inp, cAp, cBp, cCp, Wb, Wob, bih, bhh, outz, st, hout, cout);
  const int n4 = B * (T_STEPS * 5) / 4;
  norm_kernel<<<(n4 + 255) / 256, 256, 0, stream>>>(outz, st, g_out, be_out, n4, invB);
}

// Round 8
// 431.596 us; speedup vs baseline: 1.6448x; 1.2109x over previous
//
#include <hip/hip_runtime.h>

typedef short s16x8 __attribute__((ext_vector_type(8)));
typedef float f32x4 __attribute__((ext_vector_type(4)));

#define T_STEPS 128
#define BN_EPS 1e-5f
#define EROW 136   // E/H row stride in shorts (128 + 8 pad; 68 dw % 32 = 4 -> conflict-free b128)
#define LOG2E 1.4426950408889634f

__device__ __forceinline__ unsigned short f2bf(float f) {
  unsigned u = __float_as_uint(f);
  u += 0x7FFFu + ((u >> 16) & 1u);
  return (unsigned short)(u >> 16);
}
__device__ __forceinline__ unsigned cvtpk(float a, float b) {
  unsigned r;
  asm("v_cvt_pk_bf16_f32 %0, %1, %2" : "=v"(r) : "v"(a), "v"(b));
  return r;  // lo16 = bf16(a), hi16 = bf16(b)
}
__device__ __forceinline__ float sigm(float x) {
  return __builtin_amdgcn_rcpf(1.0f + __builtin_amdgcn_exp2f(x * -LOG2E));
}
__device__ __forceinline__ float tanh_(float x) {
  float r = __builtin_amdgcn_rcpf(1.0f + __builtin_amdgcn_exp2f(x * (2.0f * LOG2E)));
  return fmaf(-2.0f, r, 1.0f);
}

// ---------- fused: per-t input moments + embedding Linear/BN/ReLU fold ----------
__global__ void prep_e_kernel(const float* __restrict__ inp,
                              const float* __restrict__ W_emb, const float* __restrict__ b_emb,
                              const float* __restrict__ gamma, const float* __restrict__ beta,
                              float* __restrict__ cA, float* __restrict__ cB, float* __restrict__ cC,
                              int B, float invB) {
  int t = blockIdx.x, tid = threadIdx.x;
  float s0 = 0.f, s1 = 0.f, q0 = 0.f, q1 = 0.f, pp = 0.f;
  for (int b = tid; b < B; b += 256) {
    float2 x = *(const float2*)(inp + (size_t)b * (2 * T_STEPS) + 2 * t);
    s0 += x.x; s1 += x.y; q0 += x.x * x.x; q1 += x.y * x.y; pp += x.x * x.y;
  }
  float v[5] = {s0, s1, q0, q1, pp};
  #pragma unroll
  for (int i = 0; i < 5; ++i) {
    float x = v[i];
    #pragma unroll
    for (int o = 32; o > 0; o >>= 1) x += __shfl_down(x, o);
    v[i] = x;
  }
  __shared__ float red[4][5];
  __shared__ float tot[5];
  if ((tid & 63) == 0) {
    #pragma unroll
    for (int i = 0; i < 5; ++i) red[tid >> 6][i] = v[i];
  }
  __syncthreads();
  if (tid == 0) {
    #pragma unroll
    for (int i = 0; i < 5; ++i) tot[i] = red[0][i] + red[1][i] + red[2][i] + red[3][i];
  }
  __syncthreads();
  if (tid < 128) {
    int j = tid;
    float m0 = tot[0] * invB, m1 = tot[1] * invB;
    float q0m = tot[2] * invB, q1m = tot[3] * invB, p = tot[4] * invB;
    float v00 = q0m - m0 * m0, v11 = q1m - m1 * m1, v01 = p - m0 * m1;
    float w0 = W_emb[2 * j], w1 = W_emb[2 * j + 1];
    float mu  = w0 * m0 + w1 * m1 + b_emb[j];
    float var = w0 * w0 * v00 + w1 * w1 * v11 + 2.f * w0 * w1 * v01;
    float a = gamma[j] * rsqrtf(var + BN_EPS);
    int idx = t * 128 + j;
    cA[idx] = a * w0;
    cB[idx] = a * w1;
    cC[idx] = beta[j] + a * (b_emb[j] - mu);
  }
}

// ---------------- weights -> bf16 (gate concat + padded W_out) ----------------
__global__ void prepw_kernel(const float* __restrict__ Wih, const float* __restrict__ Whh,
                             const float* __restrict__ Wout,
                             unsigned short* __restrict__ Wb, unsigned short* __restrict__ Wob) {
  int idx = blockIdx.x * 256 + threadIdx.x;
  if (idx < 512 * 256) {
    int n = idx >> 8, k = idx & 255;
    float w = (k < 128) ? Wih[n * 128 + k] : Whh[n * 128 + (k - 128)];
    Wb[idx] = f2bf(w);
  } else if (idx < 512 * 256 + 16 * 128) {
    int i2 = idx - 512 * 256;
    int d = i2 >> 7, k = i2 & 127;
    Wob[i2] = (d < 5) ? f2bf(Wout[d * 128 + k]) : (unsigned short)0;
  }
}

// --------------------------- the recurrence ---------------------------------
// 512 thr (8 waves), 32 rows/block, ONE barrier per step.
// E and H double-buffered in LDS; phase t: G(t) reads E[rb],H[rb];
// do_e(t+1)->E[rb^1] and z(t-1) (waves 0,1, reads H[rb]) fill G's MFMA shadow;
// P(t) (depends on G's accs) writes h -> H[rb^1]; barrier.
__global__ __launch_bounds__(512, 2) void lstm_kernel(
    const float* __restrict__ inp,
    const float* __restrict__ cA, const float* __restrict__ cB, const float* __restrict__ cC,
    const unsigned short* __restrict__ Wb, const unsigned short* __restrict__ Wob,
    const float* __restrict__ bih, const float* __restrict__ bhh,
    float* __restrict__ outz, float* __restrict__ hout, float* __restrict__ cout) {
  __shared__ __align__(16) short E[2][32][EROW];   // 17408 B
  __shared__ __align__(16) short Hs[2][32][EROW];  // 17408 B

  const int tid  = threadIdx.x;
  const int wave = tid >> 6;
  const int lane = tid & 63;
  const int l15  = lane & 15;
  const int lk   = lane >> 4;        // 0..3
  const int b0   = blockIdx.x * 32;
  const int em   = tid >> 4;         // e row 0..31
  const int ec8  = (tid & 15) * 8;   // e col (8-col group)

  // --- weights to registers (once). wave owns cols [16w,16w+16) of each gate.
  s16x8 wfrag[4][8];
  #pragma unroll
  for (int g = 0; g < 4; ++g)
    #pragma unroll
    for (int kk = 0; kk < 8; ++kk)
      wfrag[g][kk] = *(const s16x8*)(Wb + (size_t)(g * 128 + wave * 16 + l15) * 256 + kk * 32 + lk * 8);
  s16x8 wof[4];
  #pragma unroll
  for (int kk = 0; kk < 4; ++kk)
    wof[kk] = *(const s16x8*)(Wob + l15 * 128 + kk * 32 + lk * 8);
  float biasg[4];
  #pragma unroll
  for (int g = 0; g < 4; ++g) {
    int n = g * 128 + wave * 16 + l15;
    biasg[g] = bih[n] + bhh[n];
  }

  float creg[2][4] = {{0.f,0.f,0.f,0.f},{0.f,0.f,0.f,0.f}};
  float hreg[2][4] = {{0.f,0.f,0.f,0.f},{0.f,0.f,0.f,0.f}};

  auto do_e = [&](int eb, int tn) {
    float2 xv = *(const float2*)(inp + (size_t)(b0 + em) * (2 * T_STEPS) + 2 * tn);
    const float4* pa = (const float4*)(cA + tn * 128 + ec8);
    const float4* pb = (const float4*)(cB + tn * 128 + ec8);
    const float4* pc = (const float4*)(cC + tn * 128 + ec8);
    unsigned w[4];
    #pragma unroll
    for (int q = 0; q < 2; ++q) {
      float4 va = pa[q], vb = pb[q], vc = pc[q];
      float e0 = fmaxf(0.f, vc.x + va.x * xv.x + vb.x * xv.y);
      float e1 = fmaxf(0.f, vc.y + va.y * xv.x + vb.y * xv.y);
      float e2 = fmaxf(0.f, vc.z + va.z * xv.x + vb.z * xv.y);
      float e3 = fmaxf(0.f, vc.w + va.w * xv.x + vb.w * xv.y);
      w[2 * q]     = cvtpk(e0, e1);
      w[2 * q + 1] = cvtpk(e2, e3);
    }
    *(uint4*)&E[eb][em][ec8] = make_uint4(w[0], w[1], w[2], w[3]);
  };

  // init: zero h-buffer0, e(0) into E[0]
  *(uint4*)&Hs[0][em][ec8] = make_uint4(0u, 0u, 0u, 0u);
  do_e(0, 0);
  __syncthreads();

  #pragma unroll 1
  for (int t = 0; t < T_STEPS; ++t) {
    const int rb = t & 1;
    const int wb = rb ^ 1;
    // --- G: gates for both 16-row groups (8 independent MFMA chains)
    f32x4 acc[2][4];
    #pragma unroll
    for (int mf = 0; mf < 2; ++mf)
      #pragma unroll
      for (int g = 0; g < 4; ++g) {
        f32x4 v = {biasg[g], biasg[g], biasg[g], biasg[g]};
        acc[mf][g] = v;
      }
    #pragma unroll
    for (int kk = 0; kk < 4; ++kk) {
      const int co = kk * 32 + lk * 8;
      s16x8 a0 = *(const s16x8*)&E[rb][l15][co];
      s16x8 a1 = *(const s16x8*)&E[rb][16 + l15][co];
      #pragma unroll
      for (int g = 0; g < 4; ++g) {
        acc[0][g] = __builtin_amdgcn_mfma_f32_16x16x32_bf16(a0, wfrag[g][kk], acc[0][g], 0, 0, 0);
        acc[1][g] = __builtin_amdgcn_mfma_f32_16x16x32_bf16(a1, wfrag[g][kk], acc[1][g], 0, 0, 0);
      }
    }
    #pragma unroll
    for (int kk = 0; kk < 4; ++kk) {
      const int co = kk * 32 + lk * 8;
      s16x8 a0 = *(const s16x8*)&Hs[rb][l15][co];
      s16x8 a1 = *(const s16x8*)&Hs[rb][16 + l15][co];
      #pragma unroll
      for (int g = 0; g < 4; ++g) {
        acc[0][g] = __builtin_amdgcn_mfma_f32_16x16x32_bf16(a0, wfrag[g][kk + 4], acc[0][g], 0, 0, 0);
        acc[1][g] = __builtin_amdgcn_mfma_f32_16x16x32_bf16(a1, wfrag[g][kk + 4], acc[1][g], 0, 0, 0);
      }
    }
    // --- aux (independent of acc): e(t+1), z(t-1) — fills the MFMA shadow
    if (t < T_STEPS - 1) do_e(wb, t + 1);
    if (t > 0 && wave < 2) {
      const int u = wave;
      f32x4 zac = {0.f, 0.f, 0.f, 0.f};
      #pragma unroll
      for (int kk = 0; kk < 4; ++kk) {
        s16x8 a = *(const s16x8*)&Hs[rb][u * 16 + l15][kk * 32 + lk * 8];
        zac = __builtin_amdgcn_mfma_f32_16x16x32_bf16(a, wof[kk], zac, 0, 0, 0);
      }
      if (l15 < 5) {
        #pragma unroll
        for (int r = 0; r < 4; ++r)
          outz[((size_t)(b0 + u * 16 + lk * 4 + r) * T_STEPS + (t - 1)) * 5 + l15] = zac[r];
      }
    }
    // --- P: pointwise update (stalls on acc; aux already issued)
    #pragma unroll
    for (int mf = 0; mf < 2; ++mf) {
      float hv[4];
      #pragma unroll
      for (int r = 0; r < 4; ++r) {
        float gi = sigm(acc[mf][0][r]);
        float gf = sigm(acc[mf][1][r]);
        float gg = tanh_(acc[mf][2][r]);
        float go = sigm(acc[mf][3][r]);
        float cc = fmaf(gf, creg[mf][r], gi * gg);
        creg[mf][r] = cc;
        float hh = go * tanh_(cc);
        hreg[mf][r] = hh; hv[r] = hh;
      }
      unsigned u01 = cvtpk(hv[0], hv[1]);
      unsigned u23 = cvtpk(hv[2], hv[3]);
      const int rp = mf * 16 + lk * 4;
      const int cw = wave * 16 + l15;
      Hs[wb][rp + 0][cw] = (short)(u01);
      Hs[wb][rp + 1][cw] = (short)(u01 >> 16);
      Hs[wb][rp + 2][cw] = (short)(u23);
      Hs[wb][rp + 3][cw] = (short)(u23 >> 16);
    }
    __syncthreads();
  }

  // tail z(127): h(127) sits in Hs[0] (written at t=127, wb=0)
  if (wave < 2) {
    const int u = wave;
    f32x4 zac = {0.f, 0.f, 0.f, 0.f};
    #pragma unroll
    for (int kk = 0; kk < 4; ++kk) {
      s16x8 a = *(const s16x8*)&Hs[0][u * 16 + l15][kk * 32 + lk * 8];
      zac = __builtin_amdgcn_mfma_f32_16x16x32_bf16(a, wof[kk], zac, 0, 0, 0);
    }
    if (l15 < 5) {
      #pragma unroll
      for (int r = 0; r < 4; ++r)
        outz[((size_t)(b0 + u * 16 + lk * 4 + r) * T_STEPS + (T_STEPS - 1)) * 5 + l15] = zac[r];
    }
  }

  // final h, c (fp32)
  #pragma unroll
  for (int mf = 0; mf < 2; ++mf)
    #pragma unroll
    for (int r = 0; r < 4; ++r) {
      int m = mf * 16 + lk * 4 + r;
      size_t base = (size_t)(b0 + m) * 128 + wave * 16 + l15;
      hout[base] = hreg[mf][r];
      cout[base] = creg[mf][r];
    }
}

// -------- output BN: non-atomic hierarchical stats + normalize --------
__global__ void zsum1_kernel(const float* __restrict__ z, float* __restrict__ pp) {
  int b = blockIdx.x;                 // 256 blocks, 32 batch rows each
  int tid = threadIdx.x;              // 256
  const float* zb = z + (size_t)b * 32 * 640;
  for (int c = tid; c < 640; c += 256) {
    float s = 0.f, q = 0.f;
    #pragma unroll 4
    for (int r = 0; r < 32; ++r) {
      float v = zb[r * 640 + c];
      s += v; q = fmaf(v, v, q);
    }
    pp[(c * 2 + 0) * 256 + b] = s;
    pp[(c * 2 + 1) * 256 + b] = q;
  }
}

__global__ void zsum2_kernel(const float* __restrict__ pp, float* __restrict__ st) {
  int j = blockIdx.x * 256 + threadIdx.x;   // 1280 outputs
  if (j < 1280) {
    const float* p = pp + (size_t)j * 256;
    float s = 0.f;
    #pragma unroll 4
    for (int i = 0; i < 256; ++i) s += p[i];
    st[j] = s;
  }
}

__global__ void norm_kernel(float* __restrict__ z, const float* __restrict__ st,
                            const float* __restrict__ gamma, const float* __restrict__ beta,
                            int n4, float invB) {
  int i = blockIdx.x * 256 + threadIdx.x;
  if (i >= n4) return;
  int c = i % 160;
  float4 v = *(const float4*)(z + (size_t)i * 4);
  float o[4] = {v.x, v.y, v.z, v.w};
  #pragma unroll
  for (int k = 0; k < 4; ++k) {
    int grp = c * 4 + k;
    int d = grp % 5;
    float S = st[grp * 2], Q = st[grp * 2 + 1];
    float mean = S * invB;
    float var  = Q * invB - mean * mean;
    float sc = gamma[d] * rsqrtf(var + BN_EPS);
    o[k] = o[k] * sc + (beta[d] - mean * sc);
  }
  float4 w = {o[0], o[1], o[2], o[3]};
  *(float4*)(z + (size_t)i * 4) = w;
}

extern "C" void kernel_launch(void* const* d_in, const int* in_sizes, int n_in,
                              void* d_out, int out_size, void* d_ws, size_t ws_size,
                              hipStream_t stream) {
  const float* inp    = (const float*)d_in[0];
  const float* W_emb  = (const float*)d_in[1];
  const float* b_emb  = (const float*)d_in[2];
  const float* g_emb  = (const float*)d_in[3];
  const float* be_emb = (const float*)d_in[4];
  const float* Wih    = (const float*)d_in[5];
  const float* bih    = (const float*)d_in[6];
  const float* Whh    = (const float*)d_in[7];
  const float* bhh    = (const float*)d_in[8];
  const float* Wout   = (const float*)d_in[9];
  // d_in[10] = b_out: cancels inside the output BatchNorm
  const float* g_out  = (const float*)d_in[11];
  const float* be_out = (const float*)d_in[12];

  const int B = in_sizes[0] / (2 * T_STEPS);   // 8192

  char* ws = (char*)d_ws;
  float*          cAp = (float*)(ws + 0);        // 64 KB
  float*          cBp = (float*)(ws + 65536);
  float*          cCp = (float*)(ws + 131072);
  unsigned short* Wb  = (unsigned short*)(ws + 196608);  // 256 KB bf16 [512][256]
  unsigned short* Wob = (unsigned short*)(ws + 458752);  // 4 KB bf16 [16][128]
  float*          st  = (float*)(ws + 462848);   // 1280 floats (finalized sum,sumsq)
  float*          pp  = (float*)(ws + 467968);   // 1280 x 256 partials (1.31 MB)

  float* outz = (float*)d_out;                   // [B][T][5] raw z, normalized in place
  float* hout = outz + (size_t)B * T_STEPS * 5;
  float* cout = hout + (size_t)B * 128;

  const float invB = 1.0f / (float)B;

  prep_e_kernel<<<T_STEPS, 256, 0, stream>>>(inp, W_emb, b_emb, g_emb, be_emb, cAp, cBp, cCp, B, invB);
  prepw_kernel<<<(512 * 256 + 16 * 128 + 255) / 256, 256, 0, stream>>>(Wih, Whh, Wout, Wb, Wob);
  lstm_kernel<<<B / 32, 512, 0, stream>>>(inp, cAp, cBp, cCp, Wb, Wob, bih, bhh, outz, hout, cout);
  zsum1_kernel<<<B / 32, 256, 0, stream>>>(outz, pp);
  zsum2_kernel<<<5, 256, 0, stream>>>(pp, st);
  const int n4 = B * (T_STEPS * 5) / 4;
  norm_kernel<<<(n4 + 255) / 256, 256, 0, stream>>>(outz, st, g_out, be_out, n4, invB);
}